// Round 4
// baseline (151.105 us; speedup 1.0000x reference)
//
#include <hip/hip_runtime.h>

// CompoundClassifier, round 4: int8 P/Q with one global scale.
//   P = x_ing @ W1[:128], Q = x_cmp @ W1[128:] + b1   (f16 intermediates)
//   global m = absmax(P,Q);  P8/Q8 = rint(x * 127/m)  (one line per row!)
//   out[e] = sigmoid( (m/127) * sum_j relu(P8[s][j]+Q8[d][j]) * W2[j] + b2 )
// Rationale (r3 counters): edge kernel was cache-BW bound; f16 P+Q = 7.68 MB
// misses per-XCD L2 (4 MiB). int8 halves bytes (512->256 MB) AND fits L2
// (3.84 MB). Common scale s>0 folds outside the reduction -> integer adds,
// no per-row scale gathers.

#define H  128
#define NI 20000
#define NC 10000
#define NE 1000000

typedef _Float16 half8  __attribute__((ext_vector_type(8)));
typedef float    floatx4 __attribute__((ext_vector_type(4)));
typedef signed char schar16 __attribute__((ext_vector_type(16)));
typedef signed char schar8  __attribute__((ext_vector_type(8)));

// ws layout: f16 tables (quant input), then int8 tables, then absmax scalar
#define P16_OFF 0                    // in halfs
#define Q16_OFF (NI * H)             // in halfs
#define F16_HALFS ((NI + NC) * H)    // 3,840,000
#define P8_B   (F16_HALFS * 2)       // byte offset 7,680,000
#define Q8_B   (P8_B + NI * H)
#define AMAX_B (P8_B + (NI + NC) * H)   // 11,520,000 (4-B aligned)

#define PB (NI / 16)   // 1250
#define QB (NC / 16)   // 625

// ---- P/Q precompute: 16x16x32 f16 MFMA (layouts verified r1/r3) + global absmax
__launch_bounds__(256)
__global__ void pq_gemm(const float* __restrict__ xin,
                        const float* __restrict__ xcmp,
                        const float* __restrict__ W1,   // [256][128] row-major
                        const float* __restrict__ b1,
                        char* __restrict__ wsb) {
    const int b    = blockIdx.x;
    const bool isQ = (b >= PB);
    const int  rb  = (isQ ? b - PB : b) * 16;
    const float* X = isQ ? xcmp : xin;
    const int kofs = isQ ? H : 0;
    _Float16* OUT  = (_Float16*)wsb + (isQ ? Q16_OFF : P16_OFF);

    const int lane = threadIdx.x & 63;
    const int w    = threadIdx.x >> 6;
    const int quad = lane >> 4;
    const int m    = lane & 15;

    half8 bf[2][4];
    float b1v[2];
#pragma unroll
    for (int nt = 0; nt < 2; ++nt) {
        const int n = w * 32 + nt * 16 + m;
#pragma unroll
        for (int ks = 0; ks < 4; ++ks) {
            const int k0 = kofs + ks * 32 + quad * 8;
#pragma unroll
            for (int j = 0; j < 8; ++j)
                bf[nt][ks][j] = (_Float16)W1[(k0 + j) * H + n];
        }
        b1v[nt] = isQ ? b1[n] : 0.0f;
    }

    half8 af[4];
    const float* xr = X + (long)(rb + m) * H + quad * 8;
#pragma unroll
    for (int ks = 0; ks < 4; ++ks) {
        float4 a = *(const float4*)(xr + ks * 32);
        float4 c = *(const float4*)(xr + ks * 32 + 4);
        half8 v = { (_Float16)a.x, (_Float16)a.y, (_Float16)a.z, (_Float16)a.w,
                    (_Float16)c.x, (_Float16)c.y, (_Float16)c.z, (_Float16)c.w };
        af[ks] = v;
    }

    floatx4 acc[2] = { (floatx4)0.0f, (floatx4)0.0f };
#pragma unroll
    for (int ks = 0; ks < 4; ++ks)
#pragma unroll
        for (int nt = 0; nt < 2; ++nt)
            acc[nt] = __builtin_amdgcn_mfma_f32_16x16x32_f16(af[ks], bf[nt][ks], acc[nt], 0, 0, 0);

    // store f16 + track block absmax (C/D: col=lane&15 within tile, row=quad*4+r)
    float lmax = 0.0f;
#pragma unroll
    for (int nt = 0; nt < 2; ++nt) {
        const int col = w * 32 + nt * 16 + m;
#pragma unroll
        for (int r = 0; r < 4; ++r) {
            const float v = acc[nt][r] + b1v[nt];
            OUT[(rb + quad * 4 + r) * H + col] = (_Float16)v;
            lmax = fmaxf(lmax, fabsf(v));
        }
    }
#pragma unroll
    for (int off = 1; off < 64; off <<= 1)
        lmax = fmaxf(lmax, __shfl_xor(lmax, off));
    __shared__ float wred[4];
    if (lane == 0) wred[w] = lmax;
    __syncthreads();
    if (threadIdx.x == 0) {
        float bm = fmaxf(fmaxf(wred[0], wred[1]), fmaxf(wred[2], wred[3]));
        atomicMax((unsigned*)(wsb + AMAX_B), __float_as_uint(bm));  // non-neg floats: uint order ok
    }
}

// ---- quantize f16 -> int8 with the global scale ----
__launch_bounds__(256)
__global__ void quant(char* __restrict__ wsb) {
    const long i = ((long)blockIdx.x * 256 + threadIdx.x) * 8;   // 1875 blocks covers 3.84M
    const float mx  = __uint_as_float(*(const unsigned*)(wsb + AMAX_B));
    const float inv = 127.0f / fmaxf(mx, 1e-20f);
    half8 v = *(const half8*)((const _Float16*)wsb + i);
    schar8 q;
#pragma unroll
    for (int j = 0; j < 8; ++j)
        q[j] = (signed char)__builtin_rintf((float)v[j] * inv);
    *(schar8*)(wsb + P8_B + i) = q;
}

// ---- edge kernel: 8 threads/edge, each owns 16 int8 of the 128-B row-line ----
__launch_bounds__(256)
__global__ void edge_mlp(const char* __restrict__ wsb,
                         const int* __restrict__ src_idx,
                         const int* __restrict__ dst_idx,
                         const float* __restrict__ W2,
                         const float* __restrict__ b2p,
                         float* __restrict__ out) {
    const int tid = threadIdx.x;
    const int c   = tid & 7;
    const int e   = blockIdx.x * 32 + (tid >> 3);

    const float mx = *(const float*)(wsb + AMAX_B);     // uniform -> scalar load
    const float s  = mx * (1.0f / 127.0f);

    const int si = src_idx[e];
    const int di = dst_idx[e];

    schar16 p = *(const schar16*)(wsb + P8_B + (long)si * H + c * 16);
    schar16 q = *(const schar16*)(wsb + Q8_B + (long)di * H + c * 16);

    const float* w2c = W2 + c * 16;
    float4 wv0 = *(const float4*)(w2c);
    float4 wv1 = *(const float4*)(w2c + 4);
    float4 wv2 = *(const float4*)(w2c + 8);
    float4 wv3 = *(const float4*)(w2c + 12);
    const float* wf = (const float*)&wv0;   // wv0..wv3 contiguous in regs? use per-vec below
    (void)wf;

    float acc = 0.0f;
#pragma unroll
    for (int j = 0; j < 4; ++j) {
        int u = (int)p[j] + (int)q[j];
        acc = fmaf(fmaxf((float)u, 0.0f), ((const float*)&wv0)[j], acc);
    }
#pragma unroll
    for (int j = 0; j < 4; ++j) {
        int u = (int)p[j + 4] + (int)q[j + 4];
        acc = fmaf(fmaxf((float)u, 0.0f), ((const float*)&wv1)[j], acc);
    }
#pragma unroll
    for (int j = 0; j < 4; ++j) {
        int u = (int)p[j + 8] + (int)q[j + 8];
        acc = fmaf(fmaxf((float)u, 0.0f), ((const float*)&wv2)[j], acc);
    }
#pragma unroll
    for (int j = 0; j < 4; ++j) {
        int u = (int)p[j + 12] + (int)q[j + 12];
        acc = fmaf(fmaxf((float)u, 0.0f), ((const float*)&wv3)[j], acc);
    }

    acc += __shfl_xor(acc, 1);
    acc += __shfl_xor(acc, 2);
    acc += __shfl_xor(acc, 4);

    if (c == 0)
        out[e] = 1.0f / (1.0f + expf(-fmaf(s, acc, b2p[0])));
}

extern "C" void kernel_launch(void* const* d_in, const int* in_sizes, int n_in,
                              void* d_out, int out_size, void* d_ws, size_t ws_size,
                              hipStream_t stream) {
    const float* xin  = (const float*)d_in[0];
    const float* xcmp = (const float*)d_in[1];
    const int*   eidx = (const int*)d_in[2];    // [2,E]: first E src, next E dst
    const float* W1   = (const float*)d_in[3];
    const float* b1   = (const float*)d_in[4];
    const float* W2   = (const float*)d_in[5];
    const float* b2   = (const float*)d_in[6];
    float* out = (float*)d_out;
    char* wsb  = (char*)d_ws;                   // ~11.5 MB used

    hipMemsetAsync(wsb + AMAX_B, 0, 4, stream);              // absmax accumulator
    hipLaunchKernelGGL(pq_gemm, dim3(PB + QB), dim3(256), 0, stream,
                       xin, xcmp, W1, b1, wsb);
    hipLaunchKernelGGL(quant, dim3(F16_HALFS / 8 / 256), dim3(256), 0, stream, wsb);
    hipLaunchKernelGGL(edge_mlp, dim3(NE / 32), dim3(256), 0, stream,
                       wsb, eidx, eidx + NE, W2, b2, out);
}

// Round 5
// 127.252 us; speedup vs baseline: 1.1874x; 1.1874x over previous
//
#include <hip/hip_runtime.h>

// CompoundClassifier, round 5: algebraic collapse (r3) + packed-f16 edge math.
//   P = x_ing @ W1[:128]        (20000x128 f16, precomputed)
//   Q = x_cmp @ W1[128:] + b1   (10000x128 f16, precomputed)
//   out[e] = sigmoid( relu(P[s]+Q[d]) . W2 + b2 )
// r4 lesson: edge kernel is VALU-ISSUE bound (53% busy, ~250 inst/wave from
// int8 byte unpack). Fix: f16 packed ops — v_pk_add_f16 + packed max +
// v_dot2_f32_f16 (2 MAC/inst, f32 acc) => ~25 VALU inst/lane-edge (~6-10x cut).
// Two launches only (quant/absmax/memset removed — they cost ~20us fixed).

#define H  128
#define NI 20000
#define NC 10000
#define NE 1000000

typedef _Float16 half2v __attribute__((ext_vector_type(2)));
typedef _Float16 half8  __attribute__((ext_vector_type(8)));
typedef float    floatx4 __attribute__((ext_vector_type(4)));

// ws layout in halfs (7.68 MB)
#define P_OFF 0
#define Q_OFF (NI * H)

#define PB (NI / 16)   // 1250
#define QB (NC / 16)   // 625

// ---- P/Q precompute: 16x16x32 f16 MFMA (fragment layouts verified r1/r3) ----
__launch_bounds__(256)
__global__ void pq_gemm(const float* __restrict__ xin,
                        const float* __restrict__ xcmp,
                        const float* __restrict__ W1,   // [256][128] row-major
                        const float* __restrict__ b1,
                        _Float16* __restrict__ ws) {
    const int b    = blockIdx.x;
    const bool isQ = (b >= PB);
    const int  rb  = (isQ ? b - PB : b) * 16;
    const float* X = isQ ? xcmp : xin;
    const int kofs = isQ ? H : 0;
    _Float16* OUT  = ws + (isQ ? Q_OFF : P_OFF);

    const int lane = threadIdx.x & 63;
    const int w    = threadIdx.x >> 6;
    const int quad = lane >> 4;
    const int m    = lane & 15;

    // B-fragments: W1 f32 -> f16 on the fly (L2-hot, broadcast across blocks)
    half8 bf[2][4];
    float b1v[2];
#pragma unroll
    for (int nt = 0; nt < 2; ++nt) {
        const int n = w * 32 + nt * 16 + m;
#pragma unroll
        for (int ks = 0; ks < 4; ++ks) {
            const int k0 = kofs + ks * 32 + quad * 8;
#pragma unroll
            for (int j = 0; j < 8; ++j)
                bf[nt][ks][j] = (_Float16)W1[(k0 + j) * H + n];
        }
        b1v[nt] = isQ ? b1[n] : 0.0f;
    }

    // A-fragments: row rb+m, contiguous 8 floats -> half8
    half8 af[4];
    const float* xr = X + (long)(rb + m) * H + quad * 8;
#pragma unroll
    for (int ks = 0; ks < 4; ++ks) {
        float4 a = *(const float4*)(xr + ks * 32);
        float4 c = *(const float4*)(xr + ks * 32 + 4);
        half8 v = { (_Float16)a.x, (_Float16)a.y, (_Float16)a.z, (_Float16)a.w,
                    (_Float16)c.x, (_Float16)c.y, (_Float16)c.z, (_Float16)c.w };
        af[ks] = v;
    }

    floatx4 acc[2] = { (floatx4)0.0f, (floatx4)0.0f };
#pragma unroll
    for (int ks = 0; ks < 4; ++ks)
#pragma unroll
        for (int nt = 0; nt < 2; ++nt)
            acc[nt] = __builtin_amdgcn_mfma_f32_16x16x32_f16(af[ks], bf[nt][ks], acc[nt], 0, 0, 0);

    // C/D: col = lane&15 within n-tile, row = quad*4 + r
#pragma unroll
    for (int nt = 0; nt < 2; ++nt) {
        const int col = w * 32 + nt * 16 + m;
#pragma unroll
        for (int r = 0; r < 4; ++r)
            OUT[(rb + quad * 4 + r) * H + col] = (_Float16)(acc[nt][r] + b1v[nt]);
    }
}

// ---- edge kernel: 8 threads/edge, packed f16 math ----
// lane c (0..7) owns halfs [c*16, c*16+16) of the 128-half row: two b128 loads
// per table, adjacent lanes contiguous -> full-line coalescing (2 lines/table).
#define EPB   160            // edges per block = 5 passes x 32
#define EGRID (NE / EPB)     // 6250 (exact)

__launch_bounds__(256)
__global__ void edge_mlp(const _Float16* __restrict__ ws,
                         const int* __restrict__ src_idx,
                         const int* __restrict__ dst_idx,
                         const float* __restrict__ W2,
                         const float* __restrict__ b2p,
                         float* __restrict__ out) {
    const int tid  = threadIdx.x;
    const int c    = tid & 7;
    const int slot = tid >> 3;      // 0..31: edge within pass

    // W2 quarter as 8 packed half2 (amortized over 5 edges)
    half2v w2h[8];
    const float* w2c = W2 + c * 16;
#pragma unroll
    for (int j = 0; j < 8; ++j) {
        half2v t = { (_Float16)w2c[2 * j], (_Float16)w2c[2 * j + 1] };
        w2h[j] = t;
    }
    const float b2v = b2p[0];

    int e  = blockIdx.x * EPB + slot;
    int si = src_idx[e];
    int di = dst_idx[e];

#pragma unroll 1
    for (int it = 0; it < 5; ++it) {
        const _Float16* pr = ws + P_OFF + (long)si * H + c * 16;
        const _Float16* qr = ws + Q_OFF + (long)di * H + c * 16;
        half8 p0 = *(const half8*)(pr);
        half8 p1 = *(const half8*)(pr + 8);
        half8 q0 = *(const half8*)(qr);
        half8 q1 = *(const half8*)(qr + 8);

        // prefetch next pass's indices while the row gathers are in flight
        int si2 = si, di2 = di;
        if (it < 4) { si2 = src_idx[e + 32]; di2 = dst_idx[e + 32]; }

        half8 h0 = p0 + q0;            // v_pk_add_f16 x4
        half8 h1 = p1 + q1;
        const half8 z = {};
#if __has_builtin(__builtin_elementwise_max)
        h0 = __builtin_elementwise_max(h0, z);   // v_pk_max_f16 x4
        h1 = __builtin_elementwise_max(h1, z);
#else
#pragma unroll
        for (int j = 0; j < 8; ++j) {
            h0[j] = h0[j] > (_Float16)0 ? h0[j] : (_Float16)0;
            h1[j] = h1[j] > (_Float16)0 ? h1[j] : (_Float16)0;
        }
#endif

        float acc = 0.0f;
#pragma unroll
        for (int j = 0; j < 4; ++j) {
            half2v a = { h0[2 * j], h0[2 * j + 1] };
#if __has_builtin(__builtin_amdgcn_fdot2)
            acc = __builtin_amdgcn_fdot2(a, w2h[j], acc, false);   // v_dot2_f32_f16
#else
            acc += (float)a[0] * (float)w2h[j][0] + (float)a[1] * (float)w2h[j][1];
#endif
        }
#pragma unroll
        for (int j = 0; j < 4; ++j) {
            half2v a = { h1[2 * j], h1[2 * j + 1] };
#if __has_builtin(__builtin_amdgcn_fdot2)
            acc = __builtin_amdgcn_fdot2(a, w2h[4 + j], acc, false);
#else
            acc += (float)a[0] * (float)w2h[4 + j][0] + (float)a[1] * (float)w2h[4 + j][1];
#endif
        }

        // reduce over the 8-lane edge group
        acc += __shfl_xor(acc, 1);
        acc += __shfl_xor(acc, 2);
        acc += __shfl_xor(acc, 4);

        if (c == 0)
            out[e] = 1.0f / (1.0f + expf(-(acc + b2v)));

        e += 32; si = si2; di = di2;
    }
}

extern "C" void kernel_launch(void* const* d_in, const int* in_sizes, int n_in,
                              void* d_out, int out_size, void* d_ws, size_t ws_size,
                              hipStream_t stream) {
    const float* xin  = (const float*)d_in[0];
    const float* xcmp = (const float*)d_in[1];
    const int*   eidx = (const int*)d_in[2];    // [2,E]: first E src, next E dst
    const float* W1   = (const float*)d_in[3];
    const float* b1   = (const float*)d_in[4];
    const float* W2   = (const float*)d_in[5];
    const float* b2   = (const float*)d_in[6];
    float* out = (float*)d_out;
    _Float16* ws = (_Float16*)d_ws;             // 7.68 MB used

    hipLaunchKernelGGL(pq_gemm, dim3(PB + QB), dim3(256), 0, stream,
                       xin, xcmp, W1, b1, ws);
    hipLaunchKernelGGL(edge_mlp, dim3(EGRID), dim3(256), 0, stream,
                       ws, eidx, eidx + NE, W2, b2, out);
}